// Round 4
// baseline (187.080 us; speedup 1.0000x reference)
//
#include <hip/hip_runtime.h>

// SVD_Solver: weighted Kabsch per (batch, joint).  B=4096, M=64, J=24.
// Round 4: single fused kernel, one block per batch.
//   stage (f4 coalesced -> padded LDS) -> 192-thread accumulate -> LDS fold ->
//   24-thread Horn-quaternion Jacobi -> LDS out-stage -> 72 coalesced f4 stores.
// No d_ws use (harness poisons it regardless; we just don't add traffic).

constexpr int M = 64;
constexpr int J = 24;
constexpr int NACC = 22;          // W, Wo[3], Wp[3], To[3], Tp[3], Sraw[9]

constexpr int WSTR = 27;          // weight row stride (24 -> 27): 2-way bank aliasing max
constexpr int OSTR = 73;          // offset row stride (72 -> 73)
constexpr int WLEN = M * WSTR;    // 1728 floats
constexpr int OLEN = M * OSTR;    // 4672 floats
constexpr int PLEN = M * 3;       // 192 floats
constexpr int KSP  = 8;           // m-split per solve
constexpr int RED  = KSP * J;     // 192 partial slots per accumulator

// Fast Jacobi rotation zeroing A[P][Q]; V accumulates eigenvectors.
template<int P, int Q>
__device__ __forceinline__ void jrot(float A[4][4], float V[4][4]) {
    float apq = A[P][Q];
    float theta = (A[Q][Q] - A[P][P]) * __builtin_amdgcn_rcpf(2.0f * apq);
    float t = __builtin_amdgcn_rcpf(fabsf(theta) + __builtin_amdgcn_sqrtf(fmaf(theta, theta, 1.0f)));
    t = (theta < 0.0f) ? -t : t;
    t = (apq == 0.0f) ? 0.0f : t;            // kills inf/NaN from rcp(0)
    float c = __builtin_amdgcn_rsqf(fmaf(t, t, 1.0f));
    float s = t * c;
#pragma unroll
    for (int k = 0; k < 4; ++k) {
        float akp = A[k][P], akq = A[k][Q];
        A[k][P] = c * akp - s * akq;
        A[k][Q] = s * akp + c * akq;
    }
#pragma unroll
    for (int k = 0; k < 4; ++k) {
        float apk = A[P][k], aqk = A[Q][k];
        A[P][k] = c * apk - s * aqk;
        A[Q][k] = s * apk + c * aqk;
        float vkp = V[k][P], vkq = V[k][Q];
        V[k][P] = c * vkp - s * vkq;
        V[k][Q] = s * vkp + c * vkq;
    }
}

__global__ __launch_bounds__(256) void kabsch_fused(
    const float* __restrict__ points,   // (B, 64, 3)
    const float* __restrict__ weight,   // (B, 64, 24)
    const float* __restrict__ offset,   // (B, 64, 24, 3)
    float* __restrict__ out,            // R: BJ*9, then t: BJ*3
    int bj_total)
{
    __shared__ float smem[WLEN + OLEN + PLEN];   // 26368 B -> ~6 blocks/CU
    float* lw = smem;                 // weight, padded stride 27
    float* lo = smem + WLEN;          // offset, padded stride 73
    float* lp = smem + WLEN + OLEN;   // points, dense
    float* red = smem + WLEN;         // overlay on lo after compute (4224 <= 4672)
    float* ost = smem;                // out-stage overlay on lw (288 <= 1728)

    const int t = threadIdx.x;
    const int b = blockIdx.x;

    // ---- stage: perfectly coalesced float4 global loads, scalar LDS scatter ----
    const float4* wg = (const float4*)(weight + (size_t)b * (M * J));
    for (int idx = t; idx < (M * J) / 4; idx += 256) {          // 384 f4
        float4 v = wg[idx];
        int g0 = idx * 4;
#pragma unroll
        for (int c = 0; c < 4; ++c) {
            int g = g0 + c;
            int m = g / J, r = g - m * J;
            lw[m * WSTR + r] = (&v.x)[c];
        }
    }
    const float4* og = (const float4*)(offset + (size_t)b * (M * J * 3));
    for (int idx = t; idx < (M * J * 3) / 4; idx += 256) {      // 1152 f4
        float4 v = og[idx];
        int g0 = idx * 4;
#pragma unroll
        for (int c = 0; c < 4; ++c) {
            int g = g0 + c;
            int m = g / (J * 3), r = g - m * (J * 3);
            lo[m * OSTR + r] = (&v.x)[c];
        }
    }
    const float4* pg = (const float4*)(points + (size_t)b * (M * 3));
    if (t < PLEN / 4) ((float4*)lp)[t] = pg[t];                 // 48 f4

    __syncthreads();

    // ---- accumulate: 192 threads, thread (j,k) sums m = k*8 .. k*8+7 ----
    float acc[NACC];
#pragma unroll
    for (int n = 0; n < NACC; ++n) acc[n] = 0.0f;

    if (t < KSP * J) {
        const int j = t % J;
        const int k = t / J;
#pragma unroll
        for (int i = 0; i < M / KSP; ++i) {
            const int m = k * (M / KSP) + i;
            float w  = lw[m * WSTR + j];
            float o0 = lo[m * OSTR + j * 3 + 0];
            float o1 = lo[m * OSTR + j * 3 + 1];
            float o2 = lo[m * OSTR + j * 3 + 2];
            float p0 = lp[m * 3 + 0];
            float p1 = lp[m * 3 + 1];
            float p2 = lp[m * 3 + 2];
            acc[0] += w;
            acc[1] = fmaf(w, o0, acc[1]);  acc[2] = fmaf(w, o1, acc[2]);  acc[3] = fmaf(w, o2, acc[3]);
            acc[4] = fmaf(w, p0, acc[4]);  acc[5] = fmaf(w, p1, acc[5]);  acc[6] = fmaf(w, p2, acc[6]);
            acc[7] += o0; acc[8] += o1; acc[9] += o2;
            acc[10] += p0; acc[11] += p1; acc[12] += p2;
            acc[13] = fmaf(o0, p0, acc[13]); acc[14] = fmaf(o0, p1, acc[14]); acc[15] = fmaf(o0, p2, acc[15]);
            acc[16] = fmaf(o1, p0, acc[16]); acc[17] = fmaf(o1, p1, acc[17]); acc[18] = fmaf(o1, p2, acc[18]);
            acc[19] = fmaf(o2, p0, acc[19]); acc[20] = fmaf(o2, p1, acc[20]); acc[21] = fmaf(o2, p2, acc[21]);
        }
    }

    __syncthreads();                    // lo reads done; red overlay now safe
    if (t < KSP * J) {
#pragma unroll
        for (int n = 0; n < NACC; ++n) red[n * RED + t] = acc[n];
    }
    __syncthreads();

    // ---- fold + solve: 24 threads, one per joint ----
    if (t < J) {
        float T[NACC];
#pragma unroll
        for (int n = 0; n < NACC; ++n) {
            float s = 0.0f;
#pragma unroll
            for (int k = 0; k < KSP; ++k) s += red[n * RED + k * J + t];
            T[n] = s;
        }
        const float inv = __builtin_amdgcn_rcpf(T[0]);
        const float cP0 = T[1] * inv, cP1 = T[2] * inv, cP2 = T[3] * inv;  // P_ centroid
        const float cQ0 = T[4] * inv, cQ1 = T[5] * inv, cQ2 = T[6] * inv;  // Q_ centroid
        const float To0 = T[7], To1 = T[8], To2 = T[9];
        const float Tp0 = T[10], Tp1 = T[11], Tp2 = T[12];
        const float fM = (float)M;
        float S00 = T[13] - cP0 * Tp0 - cQ0 * To0 + fM * cP0 * cQ0;
        float S01 = T[14] - cP0 * Tp1 - cQ1 * To0 + fM * cP0 * cQ1;
        float S02 = T[15] - cP0 * Tp2 - cQ2 * To0 + fM * cP0 * cQ2;
        float S10 = T[16] - cP1 * Tp0 - cQ0 * To1 + fM * cP1 * cQ0;
        float S11 = T[17] - cP1 * Tp1 - cQ1 * To1 + fM * cP1 * cQ1;
        float S12 = T[18] - cP1 * Tp2 - cQ2 * To1 + fM * cP1 * cQ2;
        float S20 = T[19] - cP2 * Tp0 - cQ0 * To2 + fM * cP2 * cQ0;
        float S21 = T[20] - cP2 * Tp1 - cQ1 * To2 + fM * cP2 * cQ1;
        float S22 = T[21] - cP2 * Tp2 - cQ2 * To2 + fM * cP2 * cQ2;

        // Horn's 4x4 N; max-eigvec quaternion == det-corrected SVD rotation.
        float A[4][4], V[4][4];
        A[0][0] = S00 + S11 + S22;
        A[0][1] = A[1][0] = S12 - S21;
        A[0][2] = A[2][0] = S20 - S02;
        A[0][3] = A[3][0] = S01 - S10;
        A[1][1] = S00 - S11 - S22;
        A[1][2] = A[2][1] = S01 + S10;
        A[1][3] = A[3][1] = S02 + S20;
        A[2][2] = -S00 + S11 - S22;
        A[2][3] = A[3][2] = S12 + S21;
        A[3][3] = -S00 - S11 + S22;
#pragma unroll
        for (int r = 0; r < 4; ++r)
#pragma unroll
            for (int c = 0; c < 4; ++c)
                V[r][c] = (r == c) ? 1.0f : 0.0f;

#pragma unroll 1
        for (int sweep = 0; sweep < 6; ++sweep) {
            jrot<0, 1>(A, V); jrot<0, 2>(A, V); jrot<0, 3>(A, V);
            jrot<1, 2>(A, V); jrot<1, 3>(A, V); jrot<2, 3>(A, V);
        }

        float best = A[0][0];
        float qw = V[0][0], qx = V[1][0], qy = V[2][0], qz = V[3][0];
#pragma unroll
        for (int i = 1; i < 4; ++i) {
            bool better = A[i][i] > best;
            best = better ? A[i][i] : best;
            qw = better ? V[0][i] : qw;
            qx = better ? V[1][i] : qx;
            qy = better ? V[2][i] : qy;
            qz = better ? V[3][i] : qz;
        }
        float nrm = __builtin_amdgcn_rsqf(qw * qw + qx * qx + qy * qy + qz * qz);
        qw *= nrm; qx *= nrm; qy *= nrm; qz *= nrm;

        float R00 = 1.f - 2.f * (qy * qy + qz * qz);
        float R01 = 2.f * (qx * qy - qw * qz);
        float R02 = 2.f * (qx * qz + qw * qy);
        float R10 = 2.f * (qx * qy + qw * qz);
        float R11 = 1.f - 2.f * (qx * qx + qz * qz);
        float R12 = 2.f * (qy * qz - qw * qx);
        float R20 = 2.f * (qx * qz - qw * qy);
        float R21 = 2.f * (qy * qz + qw * qx);
        float R22 = 1.f - 2.f * (qx * qx + qy * qy);

        // stage outputs in LDS in global layout: R block (216 floats) ++ t block (72)
        float* r = ost + t * 9;
        r[0] = R00; r[1] = R01; r[2] = R02;
        r[3] = R10; r[4] = R11; r[5] = R12;
        r[6] = R20; r[7] = R21; r[8] = R22;
        float* tv = ost + 216 + t * 3;
        tv[0] = cQ0 - (R00 * cP0 + R01 * cP1 + R02 * cP2);
        tv[1] = cQ1 - (R10 * cP0 + R11 * cP1 + R12 * cP2);
        tv[2] = cQ2 - (R20 * cP0 + R21 * cP1 + R22 * cP2);
    }

    __syncthreads();

    // ---- emit: 72 coalesced float4 stores (54 for R, 18 for t) ----
    if (t < 54) {
        ((float4*)(out + (size_t)b * (J * 9)))[t] = ((const float4*)ost)[t];
    } else if (t < 72) {
        ((float4*)(out + (size_t)bj_total * 9 + (size_t)b * (J * 3)))[t - 54] =
            ((const float4*)ost)[t];
    }
}

extern "C" void kernel_launch(void* const* d_in, const int* in_sizes, int n_in,
                              void* d_out, int out_size, void* d_ws, size_t ws_size,
                              hipStream_t stream) {
    const float* points = (const float*)d_in[0];
    const float* weight = (const float*)d_in[1];
    const float* offset = (const float*)d_in[2];
    float* out = (float*)d_out;

    int B = in_sizes[0] / (M * 3);   // points is (B, 64, 3)
    int bj_total = B * J;
    kabsch_fused<<<B, 256, 0, stream>>>(points, weight, offset, out, bj_total);
}

// Round 5
// 146.610 us; speedup vs baseline: 1.2760x; 1.2760x over previous
//
#include <hip/hip_runtime.h>

// SVD_Solver: weighted Kabsch per (batch, joint).  B=4096, M=64, J=24.
// Round 5: two-kernel split (R4 fusion regressed: Jacobi on 24/256 lanes behind
// barriers). accum: direct global loads (weight/offset are single-use — no LDS
// staging), 8-way m-split, in-register __shfl_xor k-reduction, zero LDS.
// solve: 1 thread/solve, Horn 4x4 + fast-intrinsic Jacobi (R3-proven).

constexpr int M = 64;
constexpr int J = 24;
constexpr int NACC = 22;          // W, Wo[3], Wp[3], To[3], Tp[3], Sraw[9]
constexpr int NWS  = 15;          // S[9], Pbar[3], Qbar[3]
constexpr int KSP  = 8;           // m-split (lane bits 3..5)
constexpr int SPW  = 8;           // solves per wave (lane bits 0..2)
constexpr int SPB  = 32;          // solves per 256-thread block

// ---- accum: grid = ceil(bj/32) blocks x 256 threads, no LDS ----
__global__ __launch_bounds__(256, 6) void accum_kernel(
    const float* __restrict__ points,   // (B, 64, 3)
    const float* __restrict__ weight,   // (B, 64, 24)
    const float* __restrict__ offset,   // (B, 64, 24, 3)
    float* __restrict__ ws,             // NWS arrays of bj_total floats (SoA)
    int bj_total)
{
    const int t    = threadIdx.x;
    const int lane = t & 63;
    const int wv   = t >> 6;            // wave in block, 0..3
    const int k    = lane >> 3;         // m-split 0..7
    const int sl   = lane & 7;          // solve-in-wave 0..7 (memory-consecutive)
    const int bj   = blockIdx.x * SPB + wv * SPW + sl;
    const int bjc  = bj < bj_total ? bj : bj_total - 1;   // clamp: garbage sums are discarded
    const int b    = bjc / J;
    const int j    = bjc - b * J;

    // thread (bj,k) handles m = k*8 + i, i = 0..7
    const float* wq = weight + (size_t)b * (M * J) + (size_t)(k * 8) * J + j;
    const float* oq = offset + ((size_t)b * (M * J) + (size_t)(k * 8) * J + j) * 3;
    const float* pq = points + (size_t)b * (M * 3) + (size_t)(k * 8) * 3;

    float acc[NACC];
#pragma unroll
    for (int n = 0; n < NACC; ++n) acc[n] = 0.0f;

#pragma unroll
    for (int i = 0; i < M / KSP; ++i) {
        float w  = wq[i * J];
        float o0 = oq[i * (J * 3) + 0];
        float o1 = oq[i * (J * 3) + 1];
        float o2 = oq[i * (J * 3) + 2];
        float p0 = pq[i * 3 + 0];
        float p1 = pq[i * 3 + 1];
        float p2 = pq[i * 3 + 2];
        acc[0] += w;
        acc[1] = fmaf(w, o0, acc[1]);  acc[2] = fmaf(w, o1, acc[2]);  acc[3] = fmaf(w, o2, acc[3]);
        acc[4] = fmaf(w, p0, acc[4]);  acc[5] = fmaf(w, p1, acc[5]);  acc[6] = fmaf(w, p2, acc[6]);
        acc[7] += o0; acc[8] += o1; acc[9] += o2;
        acc[10] += p0; acc[11] += p1; acc[12] += p2;
        acc[13] = fmaf(o0, p0, acc[13]); acc[14] = fmaf(o0, p1, acc[14]); acc[15] = fmaf(o0, p2, acc[15]);
        acc[16] = fmaf(o1, p0, acc[16]); acc[17] = fmaf(o1, p1, acc[17]); acc[18] = fmaf(o1, p2, acc[18]);
        acc[19] = fmaf(o2, p0, acc[19]); acc[20] = fmaf(o2, p1, acc[20]); acc[21] = fmaf(o2, p2, acc[21]);
    }

    // reduce over k (lane bits 3..5) entirely in-register
#pragma unroll
    for (int n = 0; n < NACC; ++n) {
        float v = acc[n];
        v += __shfl_xor(v, 8);
        v += __shfl_xor(v, 16);
        v += __shfl_xor(v, 32);
        acc[n] = v;
    }

    if (k != 0 || bj >= bj_total) return;   // lanes 0..7 of each wave write

    const float inv = __builtin_amdgcn_rcpf(acc[0]);
    const float cP0 = acc[1] * inv, cP1 = acc[2] * inv, cP2 = acc[3] * inv;
    const float cQ0 = acc[4] * inv, cQ1 = acc[5] * inv, cQ2 = acc[6] * inv;
    const float To0 = acc[7], To1 = acc[8], To2 = acc[9];
    const float Tp0 = acc[10], Tp1 = acc[11], Tp2 = acc[12];
    const float fM = (float)M;
    float Sv[NWS];
    Sv[0] = acc[13] - cP0 * Tp0 - cQ0 * To0 + fM * cP0 * cQ0;
    Sv[1] = acc[14] - cP0 * Tp1 - cQ1 * To0 + fM * cP0 * cQ1;
    Sv[2] = acc[15] - cP0 * Tp2 - cQ2 * To0 + fM * cP0 * cQ2;
    Sv[3] = acc[16] - cP1 * Tp0 - cQ0 * To1 + fM * cP1 * cQ0;
    Sv[4] = acc[17] - cP1 * Tp1 - cQ1 * To1 + fM * cP1 * cQ1;
    Sv[5] = acc[18] - cP1 * Tp2 - cQ2 * To1 + fM * cP1 * cQ2;
    Sv[6] = acc[19] - cP2 * Tp0 - cQ0 * To2 + fM * cP2 * cQ0;
    Sv[7] = acc[20] - cP2 * Tp1 - cQ1 * To2 + fM * cP2 * cQ1;
    Sv[8] = acc[21] - cP2 * Tp2 - cQ2 * To2 + fM * cP2 * cQ2;
    Sv[9]  = cP0; Sv[10] = cP1; Sv[11] = cP2;
    Sv[12] = cQ0; Sv[13] = cQ1; Sv[14] = cQ2;
#pragma unroll
    for (int n = 0; n < NWS; ++n) ws[(size_t)n * bj_total + bj] = Sv[n];
}

// ---- fast Jacobi rotation: single-instruction rcp/rsq/sqrt ----
template<int P, int Q>
__device__ __forceinline__ void jrot(float A[4][4], float V[4][4]) {
    float apq = A[P][Q];
    float theta = (A[Q][Q] - A[P][P]) * __builtin_amdgcn_rcpf(2.0f * apq);
    float t = __builtin_amdgcn_rcpf(fabsf(theta) + __builtin_amdgcn_sqrtf(fmaf(theta, theta, 1.0f)));
    t = (theta < 0.0f) ? -t : t;
    t = (apq == 0.0f) ? 0.0f : t;            // kills inf/NaN from rcp(0)
    float c = __builtin_amdgcn_rsqf(fmaf(t, t, 1.0f));
    float s = t * c;
#pragma unroll
    for (int k = 0; k < 4; ++k) {
        float akp = A[k][P], akq = A[k][Q];
        A[k][P] = c * akp - s * akq;
        A[k][Q] = s * akp + c * akq;
    }
#pragma unroll
    for (int k = 0; k < 4; ++k) {
        float apk = A[P][k], aqk = A[Q][k];
        A[P][k] = c * apk - s * aqk;
        A[Q][k] = s * apk + c * aqk;
        float vkp = V[k][P], vkq = V[k][Q];
        V[k][P] = c * vkp - s * vkq;
        V[k][Q] = s * vkp + c * vkq;
    }
}

__device__ __forceinline__ void horn_solve(
    float S00, float S01, float S02, float S10, float S11, float S12,
    float S20, float S21, float S22,
    float cP0, float cP1, float cP2, float cQ0, float cQ1, float cQ2,
    float* __restrict__ Rout, float* __restrict__ tout)
{
    float A[4][4], V[4][4];
    A[0][0] = S00 + S11 + S22;
    A[0][1] = A[1][0] = S12 - S21;
    A[0][2] = A[2][0] = S20 - S02;
    A[0][3] = A[3][0] = S01 - S10;
    A[1][1] = S00 - S11 - S22;
    A[1][2] = A[2][1] = S01 + S10;
    A[1][3] = A[3][1] = S02 + S20;
    A[2][2] = -S00 + S11 - S22;
    A[2][3] = A[3][2] = S12 + S21;
    A[3][3] = -S00 - S11 + S22;
#pragma unroll
    for (int r = 0; r < 4; ++r)
#pragma unroll
        for (int c = 0; c < 4; ++c)
            V[r][c] = (r == c) ? 1.0f : 0.0f;

#pragma unroll 1
    for (int sweep = 0; sweep < 6; ++sweep) {
        jrot<0, 1>(A, V); jrot<0, 2>(A, V); jrot<0, 3>(A, V);
        jrot<1, 2>(A, V); jrot<1, 3>(A, V); jrot<2, 3>(A, V);
    }

    float best = A[0][0];
    float qw = V[0][0], qx = V[1][0], qy = V[2][0], qz = V[3][0];
#pragma unroll
    for (int i = 1; i < 4; ++i) {
        bool better = A[i][i] > best;
        best = better ? A[i][i] : best;
        qw = better ? V[0][i] : qw;
        qx = better ? V[1][i] : qx;
        qy = better ? V[2][i] : qy;
        qz = better ? V[3][i] : qz;
    }
    float nrm = __builtin_amdgcn_rsqf(qw * qw + qx * qx + qy * qy + qz * qz);
    qw *= nrm; qx *= nrm; qy *= nrm; qz *= nrm;

    float R00 = 1.f - 2.f * (qy * qy + qz * qz);
    float R01 = 2.f * (qx * qy - qw * qz);
    float R02 = 2.f * (qx * qz + qw * qy);
    float R10 = 2.f * (qx * qy + qw * qz);
    float R11 = 1.f - 2.f * (qx * qx + qz * qz);
    float R12 = 2.f * (qy * qz - qw * qx);
    float R20 = 2.f * (qx * qz - qw * qy);
    float R21 = 2.f * (qy * qz + qw * qx);
    float R22 = 1.f - 2.f * (qx * qx + qy * qy);

    Rout[0] = R00; Rout[1] = R01; Rout[2] = R02;
    Rout[3] = R10; Rout[4] = R11; Rout[5] = R12;
    Rout[6] = R20; Rout[7] = R21; Rout[8] = R22;
    tout[0] = cQ0 - (R00 * cP0 + R01 * cP1 + R02 * cP2);
    tout[1] = cQ1 - (R10 * cP0 + R11 * cP1 + R12 * cP2);
    tout[2] = cQ2 - (R20 * cP0 + R21 * cP1 + R22 * cP2);
}

__global__ __launch_bounds__(64) void solve_kernel(
    const float* __restrict__ ws, float* __restrict__ out, int bj_total)
{
    int tid = blockIdx.x * 64 + threadIdx.x;
    if (tid >= bj_total) return;
    float Sv[NWS];
#pragma unroll
    for (int n = 0; n < NWS; ++n) Sv[n] = ws[(size_t)n * bj_total + tid];  // coalesced SoA
    float Rr[9], tr[3];
    horn_solve(Sv[0], Sv[1], Sv[2], Sv[3], Sv[4], Sv[5], Sv[6], Sv[7], Sv[8],
               Sv[9], Sv[10], Sv[11], Sv[12], Sv[13], Sv[14], Rr, tr);
    float* Rout = out + (size_t)tid * 9;
#pragma unroll
    for (int n = 0; n < 9; ++n) Rout[n] = Rr[n];
    float* tout = out + (size_t)bj_total * 9 + (size_t)tid * 3;
    tout[0] = tr[0]; tout[1] = tr[1]; tout[2] = tr[2];
}

// ---- fallback (ws too small): fused one-thread-per-solve ----
__global__ __launch_bounds__(256) void fused_kernel(
    const float* __restrict__ points, const float* __restrict__ weight,
    const float* __restrict__ offset, float* __restrict__ out, int bj_total)
{
    int tid = blockIdx.x * blockDim.x + threadIdx.x;
    if (tid >= bj_total) return;
    int b = tid / J, j = tid - b * J;
    const float* wq = weight + (size_t)b * M * J + j;
    const float* oq = offset + ((size_t)b * M * J + j) * 3;
    const float* pq = points + (size_t)b * M * 3;
    float a[NACC];
#pragma unroll
    for (int n = 0; n < NACC; ++n) a[n] = 0.0f;
#pragma unroll 4
    for (int m = 0; m < M; ++m) {
        float w = wq[m * J];
        float o0 = oq[m * (J * 3) + 0], o1 = oq[m * (J * 3) + 1], o2 = oq[m * (J * 3) + 2];
        float p0 = pq[m * 3 + 0], p1 = pq[m * 3 + 1], p2 = pq[m * 3 + 2];
        a[0] += w;
        a[1] = fmaf(w, o0, a[1]); a[2] = fmaf(w, o1, a[2]); a[3] = fmaf(w, o2, a[3]);
        a[4] = fmaf(w, p0, a[4]); a[5] = fmaf(w, p1, a[5]); a[6] = fmaf(w, p2, a[6]);
        a[7] += o0; a[8] += o1; a[9] += o2;
        a[10] += p0; a[11] += p1; a[12] += p2;
        a[13] = fmaf(o0, p0, a[13]); a[14] = fmaf(o0, p1, a[14]); a[15] = fmaf(o0, p2, a[15]);
        a[16] = fmaf(o1, p0, a[16]); a[17] = fmaf(o1, p1, a[17]); a[18] = fmaf(o1, p2, a[18]);
        a[19] = fmaf(o2, p0, a[19]); a[20] = fmaf(o2, p1, a[20]); a[21] = fmaf(o2, p2, a[21]);
    }
    float inv = __builtin_amdgcn_rcpf(a[0]);
    float cP0 = a[1] * inv, cP1 = a[2] * inv, cP2 = a[3] * inv;
    float cQ0 = a[4] * inv, cQ1 = a[5] * inv, cQ2 = a[6] * inv;
    const float fM = (float)M;
    float S00 = a[13] - cP0 * a[10] - cQ0 * a[7] + fM * cP0 * cQ0;
    float S01 = a[14] - cP0 * a[11] - cQ1 * a[7] + fM * cP0 * cQ1;
    float S02 = a[15] - cP0 * a[12] - cQ2 * a[7] + fM * cP0 * cQ2;
    float S10 = a[16] - cP1 * a[10] - cQ0 * a[8] + fM * cP1 * cQ0;
    float S11 = a[17] - cP1 * a[11] - cQ1 * a[8] + fM * cP1 * cQ1;
    float S12 = a[18] - cP1 * a[12] - cQ2 * a[8] + fM * cP1 * cQ2;
    float S20 = a[19] - cP2 * a[10] - cQ0 * a[9] + fM * cP2 * cQ0;
    float S21 = a[20] - cP2 * a[11] - cQ1 * a[9] + fM * cP2 * cQ1;
    float S22 = a[21] - cP2 * a[12] - cQ2 * a[9] + fM * cP2 * cQ2;
    float Rr[9], tr[3];
    horn_solve(S00, S01, S02, S10, S11, S12, S20, S21, S22,
               cP0, cP1, cP2, cQ0, cQ1, cQ2, Rr, tr);
    float* Rout = out + (size_t)tid * 9;
#pragma unroll
    for (int n = 0; n < 9; ++n) Rout[n] = Rr[n];
    float* tout = out + (size_t)bj_total * 9 + (size_t)tid * 3;
    tout[0] = tr[0]; tout[1] = tr[1]; tout[2] = tr[2];
}

extern "C" void kernel_launch(void* const* d_in, const int* in_sizes, int n_in,
                              void* d_out, int out_size, void* d_ws, size_t ws_size,
                              hipStream_t stream) {
    const float* points = (const float*)d_in[0];
    const float* weight = (const float*)d_in[1];
    const float* offset = (const float*)d_in[2];
    float* out = (float*)d_out;

    int B = in_sizes[0] / (M * 3);
    int bj_total = B * J;

    size_t need = (size_t)NWS * bj_total * sizeof(float);   // 5.9 MB at B=4096
    if (ws_size >= need) {
        int grid1 = (bj_total + SPB - 1) / SPB;             // 3072
        accum_kernel<<<grid1, 256, 0, stream>>>(points, weight, offset, (float*)d_ws, bj_total);
        solve_kernel<<<(bj_total + 63) / 64, 64, 0, stream>>>((const float*)d_ws, out, bj_total);
    } else {
        fused_kernel<<<(bj_total + 255) / 256, 256, 0, stream>>>(points, weight, offset, out, bj_total);
    }
}